// Round 18
// baseline (205.967 us; speedup 1.0000x reference)
//
#include <hip/hip_runtime.h>
#include <math.h>

namespace {
constexpr int Bc   = 1024;
constexpr int Lc   = 200;
constexpr int Dc   = 64;
constexpr int Ec   = 32;
constexpr int Pc   = 96;    // D+E
constexpr int Hc   = 256;
constexpr int Tc   = 8;
constexpr int NLc  = 3;
constexpr int KINc = 272;   // H+2T
constexpr int DHc  = 64;
constexpr int Cc   = 32;
constexpr int QS   = 113;   // per-head query slots: 96 xc + 16 te + 1 bias-const
constexpr int Q4   = 452;   // 4*QS
constexpr int QP   = 464;   // padded qk2 row (29 * 16)
constexpr int CG   = 112;   // per-head agg cols
constexpr int CGW  = 448;   // 4*CG
constexpr int TEBS  = Bc * Lc + 8;
constexpr float LN_EPS_V = 1e-5f;
constexpr float NEG_BIG  = -1e9f;

typedef __attribute__((ext_vector_type(8))) short bf16x8;
typedef __attribute__((ext_vector_type(4))) float f32x4;

__device__ __forceinline__ unsigned short f2bf(float f) {
    union { float f; unsigned int u; } v; v.f = f;
    unsigned int u = v.u;
    unsigned int r = (u + 0x7fffu + ((u >> 16) & 1u)) >> 16;
    return (unsigned short)r;
}
__device__ __forceinline__ float bf2f(unsigned short us) {
    union { unsigned int u; float f; } v; v.u = ((unsigned int)us) << 16;
    return v.f;
}
}

// ---------------- kpv: wvp2[i][j][t] (Wv path) + kp[i][j][t] (Wk path), one pass
__global__ __launch_bounds__(256) void k_kpv(const float* __restrict__ W_in_ctx,
                                             const float* __restrict__ b_in_ctx,
                                             const float* __restrict__ Wv,
                                             const float* __restrict__ Wk,
                                             float* __restrict__ wvp2,
                                             float* __restrict__ kp) {
    int blk = blockIdx.x;           // NLc*QS
    int i = blk / QS;
    int j = blk - i * QS;
    int t = threadIdx.x;
    __shared__ float wrow[Hc];
    if (j < 96)        wrow[t] = W_in_ctx[j * Hc + t];
    else if (j == 112) wrow[t] = b_in_ctx[t];
    __syncthreads();
    const float* WvL = Wv + (size_t)i * KINc * Hc;
    const float* WkL = Wk + (size_t)i * KINc * Hc;
    float av, ak;
    if (j >= 96 && j < 112) {
        av = WvL[(256 + (j - 96)) * Hc + t];
        ak = WkL[(256 + (j - 96)) * Hc + t];
    } else {
        av = 0.f; ak = 0.f;
        for (int c = 0; c < Hc; ++c) {
            float w = wrow[c];
            av += w * WvL[c * Hc + t];
            ak += w * WkL[c * Hc + t];
        }
    }
    wvp2[(size_t)blk * Hc + t] = av;
    kp[(size_t)blk * Hc + t]   = ak;
}

// ---------------- wbig2
__global__ __launch_bounds__(256) void k_wbig2(const float* __restrict__ Wq,
                                               const float* __restrict__ kp,
                                               float* __restrict__ wbig) {
    __shared__ float wq_l[64][65];
    __shared__ float kp_l[113][64];
    int blk = blockIdx.x;               // NLc*16
    int i = blk >> 4;
    int rem = blk & 15;
    int h = rem >> 2, et = rem & 3;
    int t = threadIdx.x;
    for (int idx = t; idx < 64 * 64; idx += 256) {
        int e = idx >> 6, d = idx & 63;
        wq_l[e][d] = Wq[(size_t)i * Hc * Hc + (size_t)(et * 64 + e) * Hc + h * 64 + d];
    }
    for (int idx = t; idx < 113 * 64; idx += 256) {
        int r = idx >> 6, d = idx & 63;
        kp_l[r][d] = kp[((size_t)i * QS + r) * Hc + h * 64 + d];
    }
    __syncthreads();
    int e  = t & 63;
    int rq = t >> 6;
    for (int r = rq; r < QS; r += 4) {
        float acc = 0.f;
        #pragma unroll
        for (int d = 0; d < 64; ++d) acc += wq_l[e][d] * kp_l[r][d];
        wbig[((size_t)i * Hc + et * 64 + e) * Q4 + h * QS + r] = 0.125f * acc;
    }
}

// ---------------- merged frag prep: wcat2F | wffF | wbigF | wroF | wclsF
__global__ __launch_bounds__(64) void k_frag(const float* __restrict__ wvp2,
                                             const float* __restrict__ Wres,
                                             const float* __restrict__ Wff1,
                                             const float* __restrict__ Wff2,
                                             const float* __restrict__ wbig,
                                             const float* __restrict__ W_ro,
                                             const float* __restrict__ W_cls,
                                             unsigned short* __restrict__ wcat2F,
                                             unsigned short* __restrict__ wffF,
                                             unsigned short* __restrict__ wbigF,
                                             unsigned short* __restrict__ wroF,
                                             unsigned short* __restrict__ wclsF) {
    int blk = blockIdx.x;
    int lane = threadIdx.x;
    unsigned short v[8];
    if (blk < NLc * 192) {
        int i = blk / 192;
        int r = blk - i * 192;
        int kk = r >> 4, ct = r & 15;
        int c = ct * 16 + (lane & 15);
        int kb = kk * 32 + (lane >> 4) * 8;
        #pragma unroll
        for (int j = 0; j < 8; ++j) {
            int k = kb + j;
            float val;
            if (k < 112)      val = wvp2[((size_t)i * QS + k) * Hc + c];
            else if (k < 368) val = Wres[(size_t)i * Hc * Hc + (size_t)(k - 112) * Hc + c];
            else              val = 0.f;
            v[j] = f2bf(val);
        }
        *(uint4*)&wcat2F[(size_t)blk * 64 * 8 + lane * 8] = *(const uint4*)v;
    } else if (blk < NLc * 192 + NLc * 256) {
        int b2 = blk - NLc * 192;
        int i = b2 / 256;
        int rem = b2 - i * 256;
        int w12 = rem >> 7;
        int r = rem & 127;
        int kk = r >> 4, ct = r & 15;
        int c = ct * 16 + (lane & 15);
        int kb = kk * 32 + (lane >> 4) * 8;
        const float* src = (w12 ? Wff2 : Wff1) + (size_t)i * Hc * Hc;
        #pragma unroll
        for (int j = 0; j < 8; ++j) v[j] = f2bf(src[(size_t)(kb + j) * Hc + c]);
        *(uint4*)&wffF[(size_t)b2 * 64 * 8 + lane * 8] = *(const uint4*)v;
    } else if (blk < NLc * 192 + NLc * 256 + NLc * 232) {
        int b3 = blk - NLc * 192 - NLc * 256;
        int i = b3 / 232;
        int r = b3 - i * 232;
        int kk = r / 29, ct = r - kk * 29;
        int c = ct * 16 + (lane & 15);
        int kb = kk * 32 + (lane >> 4) * 8;
        #pragma unroll
        for (int j = 0; j < 8; ++j) {
            float val = (c < Q4) ? wbig[((size_t)i * Hc + kb + j) * Q4 + c] : 0.f;
            v[j] = f2bf(val);
        }
        *(uint4*)&wbigF[(size_t)b3 * 64 * 8 + lane * 8] = *(const uint4*)v;
    } else if (blk < NLc * 192 + NLc * 256 + NLc * 232 + 128) {
        int b4 = blk - NLc * 192 - NLc * 256 - NLc * 232;   // 0..127
        int kk = b4 >> 4, ct = b4 & 15;
        int c = ct * 16 + (lane & 15);
        int kb = kk * 32 + (lane >> 4) * 8;
        #pragma unroll
        for (int j = 0; j < 8; ++j) v[j] = f2bf(W_ro[(size_t)(kb + j) * Hc + c]);
        *(uint4*)&wroF[(size_t)b4 * 64 * 8 + lane * 8] = *(const uint4*)v;
    } else {
        int b5 = blk - NLc * 192 - NLc * 256 - NLc * 232 - 128;  // 0..15
        int kk = b5 >> 1, ct = b5 & 1;
        int c = ct * 16 + (lane & 15);
        int kb = kk * 32 + (lane >> 4) * 8;
        #pragma unroll
        for (int j = 0; j < 8; ++j) v[j] = f2bf(W_cls[(size_t)(kb + j) * Cc + c]);
        *(uint4*)&wclsF[(size_t)b5 * 64 * 8 + lane * 8] = *(const uint4*)v;
    }
}

// ---------------- h0 = [x_u, emb[act_u]] @ W_in_self + b, fused layer-0 qk2 (MFMA)
__global__ __launch_bounds__(256) void k_h0q(const float* __restrict__ x_u,
                                             const int* __restrict__ act_u,
                                             const float* __restrict__ emb,
                                             const float* __restrict__ W,
                                             const float* __restrict__ bias,
                                             const unsigned short* __restrict__ wbigF0,
                                             float* __restrict__ h,
                                             unsigned short* __restrict__ qk2b) {
    constexpr int R = 16;
    __shared__ float xu[R * Pc];
    __shared__ __align__(16) unsigned short z1n[R * 264];
    int b0 = blockIdx.x * R;
    int t = threadIdx.x;
    for (int idx = t; idx < R * Pc; idx += 256) {
        int r = idx / Pc, j = idx - r * Pc;
        int b = b0 + r;
        float v;
        if (j < Dc) v = x_u[b * Dc + j];
        else        v = emb[act_u[b] * Ec + (j - Dc)];
        xu[idx] = v;
    }
    __syncthreads();
    float acc[R];
    float bb = bias[t];
    #pragma unroll
    for (int r = 0; r < R; ++r) acc[r] = bb;
    for (int j = 0; j < Pc; ++j) {
        float w = W[j * Hc + t];
        #pragma unroll
        for (int r = 0; r < R; ++r) acc[r] += xu[r * Pc + j] * w;
    }
    #pragma unroll
    for (int r = 0; r < R; ++r) {
        h[(size_t)(b0 + r) * Hc + t] = acc[r];
        z1n[r * 264 + t] = f2bf(acc[r]);
    }
    __syncthreads();
    int wv = t >> 6, lane = t & 63;
    int n = lane & 15, kg = lane >> 4;
    for (int ct = wv; ct < 29; ct += 4) {
        f32x4 a4 = {0.f, 0.f, 0.f, 0.f};
        for (int kk = 0; kk < 8; ++kk) {
            bf16x8 a = *(const bf16x8*)&z1n[(lane & 15) * 264 + kk * 32 + kg * 8];
            bf16x8 bbv = *(const bf16x8*)(wbigF0 + (((size_t)kk * 29 + ct) * 64 + lane) * 8);
            a4 = __builtin_amdgcn_mfma_f32_16x16x32_bf16(a, bbv, a4, 0, 0, 0);
        }
        #pragma unroll
        for (int q = 0; q < 4; ++q)
            qk2b[(size_t)(b0 + kg * 4 + q) * QP + ct * 16 + n] = f2bf(a4[q]);
    }
}

// ---------------- prep v3: xtb convert + trig-once (teb + LDS tes) + teTb from tes.
__global__ __launch_bounds__(256) void k_prep(const float* __restrict__ x_ctx,
                                              const int* __restrict__ act_ctx,
                                              const float* __restrict__ emb,
                                              const float* __restrict__ t_ctx,
                                              const float* __restrict__ freq,
                                              const float* __restrict__ phase,
                                              unsigned short* __restrict__ xtb,
                                              unsigned short* __restrict__ teb,
                                              unsigned short* __restrict__ teTb) {
    constexpr int TS = 24;      // tes row stride (shorts): 48B, 16B-aligned, 12-dword bank stride
    __shared__ float lt[Lc];
    __shared__ __align__(16) unsigned short tes[NLc * Lc * TS];
    int b = blockIdx.x;
    int t = threadIdx.x;
    if (t < Lc) lt[t] = log1pf(fmaxf(t_ctx[b * Lc + t], 0.f));
    // xtb convert (no dependence on lt)
    for (int idx = t; idx < Lc * 12; idx += 256) {
        int l = idx / 12, c8 = idx - l * 12;
        int row = b * Lc + l;
        unsigned short v[8];
        if (c8 < 8) {
            const float* s = x_ctx + (size_t)row * Dc + c8 * 8;
            float4 a0 = *(const float4*)s;
            float4 a1 = *(const float4*)(s + 4);
            v[0]=f2bf(a0.x); v[1]=f2bf(a0.y); v[2]=f2bf(a0.z); v[3]=f2bf(a0.w);
            v[4]=f2bf(a1.x); v[5]=f2bf(a1.y); v[6]=f2bf(a1.z); v[7]=f2bf(a1.w);
        } else {
            int a = act_ctx[row];
            const float* s = emb + (size_t)a * Ec + (c8 - 8) * 8;
            float4 e0 = *(const float4*)s;
            float4 e1 = *(const float4*)(s + 4);
            v[0]=f2bf(e0.x); v[1]=f2bf(e0.y); v[2]=f2bf(e0.z); v[3]=f2bf(e0.w);
            v[4]=f2bf(e1.x); v[5]=f2bf(e1.y); v[6]=f2bf(e1.z); v[7]=f2bf(e1.w);
        }
        *(uint4*)&xtb[(size_t)row * 96 + c8 * 8] = *(const uint4*)v;
    }
    __syncthreads();
    // trig once: teb (global) + tes (LDS)
    for (int idx = t; idx < NLc * Lc; idx += 256) {
        int i = idx / Lc, l = idx - i * Lc;
        float L = lt[l];
        unsigned short v[16];
        #pragma unroll
        for (int j = 0; j < 8; ++j) {
            float z = L * freq[i * Tc + j] + phase[i * Tc + j];
            v[j]     = f2bf(__sinf(z));
            v[8 + j] = f2bf(__cosf(z));
        }
        size_t base = ((size_t)i * TEBS + b * Lc + l) * 16;
        *(uint4*)&teb[base]     = *(const uint4*)v;
        *(uint4*)&teb[base + 8] = *(const uint4*)&v[8];
        *(uint4*)&tes[idx * TS]     = *(const uint4*)v;
        *(uint4*)&tes[idx * TS + 8] = *(const uint4*)&v[8];
    }
    __syncthreads();
    // teTb from tes (no recompute)
    for (int idx = t; idx < NLc * 16 * 28; idx += 256) {
        int i  = idx / 448;
        int r2 = idx - i * 448;
        int f  = r2 / 28, ch = r2 - f * 28;
        int l0 = ch * 8;
        unsigned short v[8];
        #pragma unroll
        for (int k = 0; k < 8; ++k) {
            int l = l0 + k;
            v[k] = (l < Lc) ? tes[(i * Lc + l) * TS + f] : (unsigned short)0;
        }
        *(uint4*)&teTb[((size_t)i * Bc * 16 + b * 16 + f) * 224 + l0] = *(const uint4*)v;
    }
}

// ---------------- fused attention (R12 form). One block per b, 8 waves.
__global__ __launch_bounds__(512) void k_att(const int* __restrict__ act_ctx,
                                             const unsigned short* __restrict__ qk2b,
                                             const unsigned short* __restrict__ xtb,
                                             const unsigned short* __restrict__ teb_l,
                                             const unsigned short* __restrict__ teTb_l,
                                             float* __restrict__ cagg) {
    constexpr int XS = 112;
    __shared__ __align__(16) unsigned short xt[208 * XS];
    __shared__ unsigned short qks[QP];
    __shared__ float S[4][208];
    __shared__ unsigned short Pl[16][232];
    int b = blockIdx.x;
    int t = threadIdx.x;
    int wv = t >> 6, lane = t & 63;
    int kg = lane >> 4;

    if (t < QP / 2) ((unsigned int*)qks)[t] = ((const unsigned int*)(qk2b + (size_t)b * QP))[t];
    for (int idx = t; idx < 16 * 29; idx += 512) {
        int row = idx / 29, c8 = idx - row * 29;
        uint4 z = {0, 0, 0, 0};
        *(uint4*)&Pl[row][c8 * 8] = z;
    }
    const unsigned short* xrow = xtb + (size_t)b * Lc * 96;
    for (int idx = t; idx < Lc * 12; idx += 512) {
        int l = idx / 12, c8 = idx - l * 12;
        uint4 v = *(const uint4*)(xrow + (size_t)l * 96 + c8 * 8);
        *(uint4*)&xt[l * XS + c8 * 8] = v;
    }
    for (int idx = t; idx < 8 * 12; idx += 512) {
        int l = 200 + idx / 12, c8 = idx - (idx / 12) * 12;
        uint4 z = {0, 0, 0, 0};
        *(uint4*)&xt[l * XS + c8 * 8] = z;
    }
    __syncthreads();

    bf16x8 bfr[4];
    {
        int h = lane & 15;
        int kb = kg * 8;
        #pragma unroll
        for (int kk = 0; kk < 4; ++kk) {
            unsigned short tmp[8];
            #pragma unroll
            for (int j = 0; j < 8; ++j) {
                int k = kk * 32 + kb + j;
                tmp[j] = (h < 4 && k < QS) ? qks[h * QS + k] : (unsigned short)0;
            }
            bfr[kk] = *(const bf16x8*)tmp;
        }
    }

    const unsigned short* terow = teb_l + (size_t)b * Lc * 16;
    for (int tile = wv; tile < 13; tile += 8) {
        int r = tile * 16 + (lane & 15);
        bf16x8 a0 = *(const bf16x8*)&xt[r * XS + kg * 8];
        bf16x8 a1 = *(const bf16x8*)&xt[r * XS + 32 + kg * 8];
        bf16x8 a2 = *(const bf16x8*)&xt[r * XS + 64 + kg * 8];
        bf16x8 a3;
        if (kg < 2) {
            a3 = *(const bf16x8*)(terow + (size_t)r * 16 + kg * 8);
        } else if (kg == 2) {
            unsigned short tmp[8] = {0x3F80u, 0, 0, 0, 0, 0, 0, 0};
            a3 = *(const bf16x8*)tmp;
        } else {
            bf16x8 z = {0, 0, 0, 0, 0, 0, 0, 0};
            a3 = z;
        }
        f32x4 acc = {0.f, 0.f, 0.f, 0.f};
        acc = __builtin_amdgcn_mfma_f32_16x16x32_bf16(a0, bfr[0], acc, 0, 0, 0);
        acc = __builtin_amdgcn_mfma_f32_16x16x32_bf16(a1, bfr[1], acc, 0, 0, 0);
        acc = __builtin_amdgcn_mfma_f32_16x16x32_bf16(a2, bfr[2], acc, 0, 0, 0);
        acc = __builtin_amdgcn_mfma_f32_16x16x32_bf16(a3, bfr[3], acc, 0, 0, 0);
        int h = lane & 15;
        if (h < 4) {
            int rb = tile * 16 + kg * 4;
            #pragma unroll
            for (int q = 0; q < 4; ++q) S[h][rb + q] = acc[q];
        }
    }
    __syncthreads();

    if (wv < 4) {
        int h = wv;
        float lv[4];
        #pragma unroll
        for (int k = 0; k < 4; ++k) {
            int l = lane + 64 * k;
            if (l < Lc) lv[k] = (act_ctx[b * Lc + l] > 0) ? S[h][l] : NEG_BIG;
            else        lv[k] = -INFINITY;
        }
        float m = fmaxf(fmaxf(lv[0], lv[1]), fmaxf(lv[2], lv[3]));
        #pragma unroll
        for (int off = 32; off >= 1; off >>= 1) m = fmaxf(m, __shfl_xor(m, off));
        float p[4];
        float ssum = 0.f;
        #pragma unroll
        for (int k = 0; k < 4; ++k) {
            int l = lane + 64 * k;
            p[k] = (l < Lc) ? __expf(lv[k] - m) : 0.f;
            ssum += p[k];
        }
        #pragma unroll
        for (int off = 32; off >= 1; off >>= 1) ssum += __shfl_xor(ssum, off);
        float sinv = 1.f / ssum;
        #pragma unroll
        for (int k = 0; k < 4; ++k) {
            int l = lane + 64 * k;
            if (l < Lc) Pl[wv][l] = f2bf(p[k] * sinv);
        }
    }
    __syncthreads();

    const unsigned short* teT = teTb_l + (size_t)b * 16 * 224;
    if (wv < 7) {
        int tile = wv;
        int n = lane & 15;
        f32x4 acc = {0.f, 0.f, 0.f, 0.f};
        #pragma unroll
        for (int kk = 0; kk < 7; ++kk) {
            bf16x8 a = *(const bf16x8*)&Pl[lane & 15][kk * 32 + kg * 8];
            bf16x8 bb;
            if (tile < 6) {
                unsigned short tmp[8];
                #pragma unroll
                for (int jj = 0; jj < 8; ++jj)
                    tmp[jj] = xt[(kk * 32 + kg * 8 + jj) * XS + tile * 16 + n];
                bb = *(const bf16x8*)tmp;
            } else {
                bb = *(const bf16x8*)(teT + (size_t)n * 224 + kk * 32 + kg * 8);
            }
            acc = __builtin_amdgcn_mfma_f32_16x16x32_bf16(a, bb, acc, 0, 0, 0);
        }
        if (kg == 0) {
            #pragma unroll
            for (int q = 0; q < 4; ++q)
                cagg[(size_t)b * CGW + q * CG + tile * 16 + n] = acc[q];
        }
    }
}

// ---------------- fused post chain + next-layer qk2 (or head on last layer).
__global__ __launch_bounds__(512) void k_postq(const float* __restrict__ cagg,
                                               float* __restrict__ h,
                                               const float* __restrict__ wvp2L,
                                               const unsigned short* __restrict__ wcat2F_l,
                                               const unsigned short* __restrict__ wff1F_l,
                                               const unsigned short* __restrict__ wff2F_l,
                                               const float* __restrict__ bresL,
                                               const float* __restrict__ bff1L,
                                               const float* __restrict__ bff2L,
                                               const float* __restrict__ g1L,
                                               const float* __restrict__ beta1L,
                                               const float* __restrict__ g2L,
                                               const float* __restrict__ beta2L,
                                               const unsigned short* __restrict__ wbigF_next,
                                               unsigned short* __restrict__ qk2b,
                                               const unsigned short* __restrict__ wroF,
                                               const unsigned short* __restrict__ wclsF,
                                               const float* __restrict__ b_ro,
                                               const float* __restrict__ b_cls,
                                               const float* __restrict__ W_dt,
                                               const float* __restrict__ b_dt,
                                               const float* __restrict__ W_rem,
                                               const float* __restrict__ b_rem,
                                               float* __restrict__ out) {
    __shared__ __align__(16) unsigned short Xa[16 * 712];
    __shared__ float z1f[16 * 260];
    __shared__ __align__(16) unsigned short z1n[16 * 264];
    __shared__ __align__(16) unsigned short fb16[16 * 264];
    int r0 = blockIdx.x * 16;
    int t = threadIdx.x;
    int wv = t >> 6, lane = t & 63;
    int n = lane & 15, kg = lane >> 4;
    const bf16x8 zf = {0, 0, 0, 0, 0, 0, 0, 0};

    for (int idx = t; idx < 16 * 704; idx += 512) {
        int r = idx / 704, c = idx - r * 704;
        float v = (c < 448) ? cagg[(size_t)(r0 + r) * CGW + c]
                            : h[(size_t)(r0 + r) * Hc + (c - 448)];
        Xa[r * 712 + c] = f2bf(v);
    }
    __syncthreads();

    // GEMM1: block-diagonal, K=384.
    {
        int hh = wv >> 1;
        f32x4 acc0 = {0.f,0.f,0.f,0.f}, acc1 = {0.f,0.f,0.f,0.f};
        #pragma unroll
        for (int kk = 0; kk < 12; ++kk) {
            int k0 = kk * 32 + kg * 8;
            bf16x8 a;
            if (k0 < 112)      a = *(const bf16x8*)&Xa[(lane & 15) * 712 + hh * 112 + k0];
            else if (k0 < 368) a = *(const bf16x8*)&Xa[(lane & 15) * 712 + 448 + (k0 - 112)];
            else               a = zf;
            bf16x8 b0 = *(const bf16x8*)(wcat2F_l + (((size_t)kk * 16 + wv * 2) * 64 + lane) * 8);
            bf16x8 b1 = *(const bf16x8*)(wcat2F_l + (((size_t)kk * 16 + wv * 2 + 1) * 64 + lane) * 8);
            acc0 = __builtin_amdgcn_mfma_f32_16x16x32_bf16(a, b0, acc0, 0, 0, 0);
            acc1 = __builtin_amdgcn_mfma_f32_16x16x32_bf16(a, b1, acc1, 0, 0, 0);
        }
        int c0 = (wv * 2) * 16 + n, c1 = (wv * 2 + 1) * 16 + n;
        float bi0 = bresL[c0] + wvp2L[112 * Hc + c0];
        float bi1 = bresL[c1] + wvp2L[112 * Hc + c1];
        #pragma unroll
        for (int q = 0; q < 4; ++q) {
            z1f[(kg * 4 + q) * 260 + c0] = acc0[q] + bi0;
            z1f[(kg * 4 + q) * 260 + c1] = acc1[q] + bi1;
        }
    }
    __syncthreads();
    if (wv < 4) {
        int row = wv * 4 + kg;
        float sm = 0.f, sq = 0.f, vals[16];
        #pragma unroll
        for (int s = 0; s < 16; ++s) {
            float v = z1f[row * 260 + n + 16 * s];
            vals[s] = v; sm += v; sq += v * v;
        }
        #pragma unroll
        for (int off = 8; off >= 1; off >>= 1) { sm += __shfl_xor(sm, off); sq += __shfl_xor(sq, off); }
        float mu = sm * (1.f / 256.f);
        float rstd = rsqrtf(sq * (1.f / 256.f) - mu * mu + LN_EPS_V);
        #pragma unroll
        for (int s = 0; s < 16; ++s) {
            int c = n + 16 * s;
            float v = (vals[s] - mu) * rstd * g1L[c] + beta1L[c];
            z1f[row * 260 + c] = v;
            z1n[row * 264 + c] = f2bf(v);
        }
    }
    __syncthreads();
    // GEMM2 (FF1) -> relu
    {
        f32x4 acc0 = {0.f,0.f,0.f,0.f}, acc1 = {0.f,0.f,0.f,0.f};
        for (int kk = 0; kk < 8; ++kk) {
            bf16x8 a = *(const bf16x8*)&z1n[(lane & 15) * 264 + kk * 32 + kg * 8];
            bf16x8 b0 = *(const bf16x8*)(wff1F_l + (((size_t)kk * 16 + wv * 2) * 64 + lane) * 8);
            bf16x8 b1 = *(const bf16x8*)(wff1F_l + (((size_t)kk * 16 + wv * 2 + 1) * 64 + lane) * 8);
            acc0 = __builtin_amdgcn_mfma_f32_16x16x32_bf16(a, b0, acc0, 0, 0, 0);
            acc1 = __builtin_amdgcn_mfma_f32_16x16x32_bf16(a, b1, acc1, 0, 0, 0);
        }
        int c0 = (wv * 2) * 16 + n, c1 = (wv * 2 + 1) * 16 + n;
        float bi0 = bff1L[c0], bi1 = bff1L[c1];
        #pragma unroll
        for (int q = 0; q < 4; ++q) {
            fb16[(kg * 4 + q) * 264 + c0] = f2bf(fmaxf(acc0[q] + bi0, 0.f));
            fb16[(kg * 4 + q) * 264 + c1] = f2bf(fmaxf(acc1[q] + bi1, 0.f));
        }
    }
    __syncthreads();
    // GEMM3 (FF2) + residual
    {
        f32x4 acc0 = {0.f,0.f,0.f,0.f}, acc1 = {0.f,0.f,0.f,0.f};
        for (int kk = 0; kk < 8; ++kk) {
            bf16x8 a = *(const bf16x8*)&fb16[(lane & 15) * 264 + kk * 32 + kg * 8];
            bf16x8 b0 = *(const bf16x8*)(wff2F_l + (((size_t)kk * 16 + wv * 2) * 64 + lane) * 8);
            bf16x8 b1 = *(const bf16x8*)(wff2F_l + (((size_t)kk * 16 + wv * 2 + 1) * 64 + lane) * 8);
            acc0 = __builtin_amdgcn_mfma_f32_16x16x32_bf16(a, b0, acc0, 0, 0, 0);
            acc1 = __builtin_amdgcn_mfma_f32_16x16x32_bf16(a, b1, acc1, 0, 0, 0);
        }
        int c0 = (wv * 2) * 16 + n, c1 = (wv * 2 + 1) * 16 + n;
        float bi0 = bff2L[c0], bi1 = bff2L[c1];
        #pragma unroll
        for (int q = 0; q < 4; ++q) {
            int row = kg * 4 + q;
            z1f[row * 260 + c0] = acc0[q] + bi0 + z1f[row * 260 + c0];
            z1f[row * 260 + c1] = acc1[q] + bi1 + z1f[row * 260 + c1];
        }
    }
    __syncthreads();
    // LN2 -> h + z1n
    if (wv < 4) {
        int row = wv * 4 + kg;
        float sm = 0.f, sq = 0.f, vals[16];
        #pragma unroll
        for (int s = 0; s < 16; ++s) {
            float v = z1f[row * 260 + n + 16 * s];
            vals[s] = v; sm += v; sq += v * v;
        }
        #pragma unroll
        for (int off = 8; off >= 1; off >>= 1) { sm += __shfl_xor(sm, off); sq += __shfl_xor(sq, off); }
        float mu = sm * (1.f / 256.f);
        float rstd = rsqrtf(sq * (1.f / 256.f) - mu * mu + LN_EPS_V);
        #pragma unroll
        for (int s = 0; s < 16; ++s) {
            int c = n + 16 * s;
            float v = (vals[s] - mu) * rstd * g2L[c] + beta2L[c];
            h[(size_t)(r0 + row) * Hc + c] = v;
            z1n[row * 264 + c] = f2bf(v);
        }
    }
    __syncthreads();
    if (wbigF_next) {
        for (int ct = wv; ct < 29; ct += 8) {
            f32x4 acc = {0.f, 0.f, 0.f, 0.f};
            for (int kk = 0; kk < 8; ++kk) {
                bf16x8 a = *(const bf16x8*)&z1n[(lane & 15) * 264 + kk * 32 + kg * 8];
                bf16x8 bb = *(const bf16x8*)(wbigF_next + (((size_t)kk * 29 + ct) * 64 + lane) * 8);
                acc = __builtin_amdgcn_mfma_f32_16x16x32_bf16(a, bb, acc, 0, 0, 0);
            }
            #pragma unroll
            for (int q = 0; q < 4; ++q)
                qk2b[(size_t)(r0 + kg * 4 + q) * QP + ct * 16 + n] = f2bf(acc[q]);
        }
    } else {
        // ---- fused head ----
        {
            f32x4 acc0 = {0.f,0.f,0.f,0.f}, acc1 = {0.f,0.f,0.f,0.f};
            for (int kk = 0; kk < 8; ++kk) {
                bf16x8 a = *(const bf16x8*)&z1n[(lane & 15) * 264 + kk * 32 + kg * 8];
                bf16x8 b0 = *(const bf16x8*)(wroF + (((size_t)kk * 16 + wv * 2) * 64 + lane) * 8);
                bf16x8 b1 = *(const bf16x8*)(wroF + (((size_t)kk * 16 + wv * 2 + 1) * 64 + lane) * 8);
                acc0 = __builtin_amdgcn_mfma_f32_16x16x32_bf16(a, b0, acc0, 0, 0, 0);
                acc1 = __builtin_amdgcn_mfma_f32_16x16x32_bf16(a, b1, acc1, 0, 0, 0);
            }
            int c0 = (wv * 2) * 16 + n, c1 = (wv * 2 + 1) * 16 + n;
            float bi0 = b_ro[c0], bi1 = b_ro[c1];
            #pragma unroll
            for (int q = 0; q < 4; ++q) {
                fb16[(kg * 4 + q) * 264 + c0] = f2bf(fmaxf(acc0[q] + bi0, 0.f));
                fb16[(kg * 4 + q) * 264 + c1] = f2bf(fmaxf(acc1[q] + bi1, 0.f));
            }
        }
        __syncthreads();
        if (wv < 2) {
            int ct = wv;
            f32x4 acc = {0.f, 0.f, 0.f, 0.f};
            for (int kk = 0; kk < 8; ++kk) {
                bf16x8 a = *(const bf16x8*)&fb16[(lane & 15) * 264 + kk * 32 + kg * 8];
                bf16x8 bb = *(const bf16x8*)(wclsF + (((size_t)kk * 2 + ct) * 64 + lane) * 8);
                acc = __builtin_amdgcn_mfma_f32_16x16x32_bf16(a, bb, acc, 0, 0, 0);
            }
            int c = ct * 16 + n;
            float bc = b_cls[c];
            #pragma unroll
            for (int q = 0; q < 4; ++q)
                out[(size_t)(r0 + kg * 4 + q) * Cc + c] = acc[q] + bc;
        }
        #pragma unroll
        for (int u = 0; u < 2; ++u) {
            int row = wv * 2 + u;
            float sd = 0.f, sr = 0.f;
            #pragma unroll
            for (int k2 = 0; k2 < 4; ++k2) {
                int c = lane + 64 * k2;
                float zv = bf2f(fb16[row * 264 + c]);
                sd += zv * W_dt[c];
                sr += zv * W_rem[c];
            }
            #pragma unroll
            for (int off = 32; off >= 1; off >>= 1) { sd += __shfl_xor(sd, off); sr += __shfl_xor(sr, off); }
            if (lane == 0) {
                out[(size_t)Bc * Cc + (r0 + row)]      = 1.f / (1.f + __expf(-(sd + b_dt[0])));
                out[(size_t)Bc * Cc + Bc + (r0 + row)] = 1.f / (1.f + __expf(-(sr + b_rem[0])));
            }
        }
    }
}

extern "C" void kernel_launch(void* const* d_in, const int* in_sizes, int n_in,
                              void* d_out, int out_size, void* d_ws, size_t ws_size,
                              hipStream_t stream) {
    const float* x_u      = (const float*)d_in[0];
    const float* x_ctx    = (const float*)d_in[1];
    const float* t_ctx    = (const float*)d_in[2];
    const int*   act_u    = (const int*)d_in[3];
    const int*   act_ctx  = (const int*)d_in[4];
    const float* emb      = (const float*)d_in[5];
    const float* W_in_self = (const float*)d_in[6];
    const float* b_in_self = (const float*)d_in[7];
    const float* W_in_ctx  = (const float*)d_in[8];
    const float* b_in_ctx  = (const float*)d_in[9];
    const float* freq  = (const float*)d_in[10];
    const float* phase = (const float*)d_in[11];
    const float* Wq    = (const float*)d_in[12];
    const float* Wk    = (const float*)d_in[13];
    const float* Wv    = (const float*)d_in[14];
    const float* Wres  = (const float*)d_in[15];
    const float* bres  = (const float*)d_in[16];
    const float* Wff1  = (const float*)d_in[17];
    const float* bff1  = (const float*)d_in[18];
    const float* Wff2  = (const float*)d_in[19];
    const float* bff2  = (const float*)d_in[20];
    const float* g1    = (const float*)d_in[21];
    const float* beta1 = (const float*)d_in[22];
    const float* g2    = (const float*)d_in[23];
    const float* beta2 = (const float*)d_in[24];
    const float* W_ro  = (const float*)d_in[25];
    const float* b_ro  = (const float*)d_in[26];
    const float* W_cls = (const float*)d_in[27];
    const float* b_cls = (const float*)d_in[28];
    const float* W_dt  = (const float*)d_in[29];
    const float* b_dt  = (const float*)d_in[30];
    const float* W_rem = (const float*)d_in[31];
    const float* b_rem = (const float*)d_in[32];

    float* ws    = (float*)d_ws;
    float* hbuf  = ws;                                    // B*H
    float* wbig  = hbuf  + (size_t)Bc * Hc;               // NL*H*Q4
    float* cagg2 = wbig  + (size_t)NLc * Hc * Q4;         // B*CGW
    float* wvp2  = cagg2 + (size_t)Bc * CGW;              // NL*QS*H
    float* kp    = wvp2  + (size_t)NLc * QS * Hc;         // NL*QS*H
    unsigned short* xtb   = (unsigned short*)(kp + (size_t)NLc * QS * Hc);
    unsigned short* teb   = xtb   + (size_t)Bc * Lc * 96;
    unsigned short* teTb  = teb   + (size_t)NLc * TEBS * 16;
    unsigned short* qk2b  = teTb  + (size_t)NLc * Bc * 16 * 224;
    unsigned short* wcat2F = qk2b + (size_t)Bc * QP;      // NL*192*512
    unsigned short* wffF  = wcat2F + (size_t)NLc * 192 * 512;
    unsigned short* wbigF = wffF  + (size_t)NLc * 2 * 128 * 512;
    unsigned short* wroF  = wbigF + (size_t)NLc * 232 * 512;   // 128*512
    unsigned short* wclsF = wroF  + (size_t)128 * 512;         // 16*512
    size_t need = ((size_t)Bc * Hc + (size_t)NLc * Hc * Q4
                  + (size_t)Bc * CGW + 2 * (size_t)NLc * QS * Hc) * 4
                + ((size_t)Bc * Lc * 96
                  + (size_t)NLc * TEBS * 16 + (size_t)NLc * Bc * 16 * 224
                  + (size_t)Bc * QP
                  + (size_t)NLc * 192 * 512 + (size_t)NLc * 2 * 128 * 512
                  + (size_t)NLc * 232 * 512 + (size_t)144 * 512) * 2;
    if (ws_size < need) return;

    float* out = (float*)d_out;

    k_kpv<<<NLc * QS, 256, 0, stream>>>(W_in_ctx, b_in_ctx, Wv, Wk, wvp2, kp);
    k_wbig2<<<NLc * 16, 256, 0, stream>>>(Wq, kp, wbig);
    k_frag<<<NLc * (192 + 256 + 232) + 144, 64, 0, stream>>>(wvp2, Wres, Wff1, Wff2, wbig,
                                                             W_ro, W_cls,
                                                             wcat2F, wffF, wbigF, wroF, wclsF);
    k_prep<<<Bc, 256, 0, stream>>>(x_ctx, act_ctx, emb, t_ctx, freq, phase, xtb, teb, teTb);
    k_h0q<<<Bc / 16, 256, 0, stream>>>(x_u, act_u, emb, W_in_self, b_in_self,
                                       wbigF, hbuf, qk2b);

    for (int i = 0; i < NLc; ++i) {
        k_att<<<Bc, 512, 0, stream>>>(act_ctx, qk2b, xtb,
                                      teb + (size_t)i * TEBS * 16,
                                      teTb + (size_t)i * Bc * 16 * 224, cagg2);
        const unsigned short* wbnext = (i < NLc - 1) ? (wbigF + (size_t)(i + 1) * 232 * 512)
                                                     : (const unsigned short*)nullptr;
        k_postq<<<Bc / 16, 512, 0, stream>>>(cagg2, hbuf,
                                             wvp2 + (size_t)i * QS * Hc,
                                             wcat2F + (size_t)i * 192 * 512,
                                             wffF + (size_t)(i * 2) * 128 * 512,
                                             wffF + (size_t)(i * 2 + 1) * 128 * 512,
                                             bres + i * Hc, bff1 + i * Hc, bff2 + i * Hc,
                                             g1 + i * Hc, beta1 + i * Hc,
                                             g2 + i * Hc, beta2 + i * Hc,
                                             wbnext, qk2b,
                                             wroF, wclsF, b_ro, b_cls,
                                             W_dt, b_dt, W_rem, b_rem, out);
    }
}

// Round 19
// 199.737 us; speedup vs baseline: 1.0312x; 1.0312x over previous
//
#include <hip/hip_runtime.h>
#include <math.h>

namespace {
constexpr int Bc   = 1024;
constexpr int Lc   = 200;
constexpr int Dc   = 64;
constexpr int Ec   = 32;
constexpr int Pc   = 96;    // D+E
constexpr int Hc   = 256;
constexpr int Tc   = 8;
constexpr int NLc  = 3;
constexpr int KINc = 272;   // H+2T
constexpr int DHc  = 64;
constexpr int Cc   = 32;
constexpr int QS   = 113;   // per-head query slots: 96 xc + 16 te + 1 bias-const
constexpr int Q4   = 452;   // 4*QS
constexpr int QP   = 464;   // padded qk2 row (29 * 16)
constexpr int CG   = 112;   // per-head agg cols
constexpr int CGW  = 448;   // 4*CG
constexpr int TEBS  = Bc * Lc + 8;
constexpr float LN_EPS_V = 1e-5f;
constexpr float NEG_BIG  = -1e9f;

typedef __attribute__((ext_vector_type(8))) short bf16x8;
typedef __attribute__((ext_vector_type(4))) float f32x4;

__device__ __forceinline__ unsigned short f2bf(float f) {
    union { float f; unsigned int u; } v; v.f = f;
    unsigned int u = v.u;
    unsigned int r = (u + 0x7fffu + ((u >> 16) & 1u)) >> 16;
    return (unsigned short)r;
}
__device__ __forceinline__ float bf2f(unsigned short us) {
    union { unsigned int u; float f; } v; v.u = ((unsigned int)us) << 16;
    return v.f;
}
}

// ---------------- kpv: wvp2[i][j][t] (Wv path) + kp[i][j][t] (Wk path), one pass
__global__ __launch_bounds__(256) void k_kpv(const float* __restrict__ W_in_ctx,
                                             const float* __restrict__ b_in_ctx,
                                             const float* __restrict__ Wv,
                                             const float* __restrict__ Wk,
                                             float* __restrict__ wvp2,
                                             float* __restrict__ kp) {
    int blk = blockIdx.x;           // NLc*QS
    int i = blk / QS;
    int j = blk - i * QS;
    int t = threadIdx.x;
    __shared__ float wrow[Hc];
    if (j < 96)        wrow[t] = W_in_ctx[j * Hc + t];
    else if (j == 112) wrow[t] = b_in_ctx[t];
    __syncthreads();
    const float* WvL = Wv + (size_t)i * KINc * Hc;
    const float* WkL = Wk + (size_t)i * KINc * Hc;
    float av, ak;
    if (j >= 96 && j < 112) {
        av = WvL[(256 + (j - 96)) * Hc + t];
        ak = WkL[(256 + (j - 96)) * Hc + t];
    } else {
        av = 0.f; ak = 0.f;
        for (int c = 0; c < Hc; ++c) {
            float w = wrow[c];
            av += w * WvL[c * Hc + t];
            ak += w * WkL[c * Hc + t];
        }
    }
    wvp2[(size_t)blk * Hc + t] = av;
    kp[(size_t)blk * Hc + t]   = ak;
}

// ---------------- wbig2
__global__ __launch_bounds__(256) void k_wbig2(const float* __restrict__ Wq,
                                               const float* __restrict__ kp,
                                               float* __restrict__ wbig) {
    __shared__ float wq_l[64][65];
    __shared__ float kp_l[113][64];
    int blk = blockIdx.x;               // NLc*16
    int i = blk >> 4;
    int rem = blk & 15;
    int h = rem >> 2, et = rem & 3;
    int t = threadIdx.x;
    for (int idx = t; idx < 64 * 64; idx += 256) {
        int e = idx >> 6, d = idx & 63;
        wq_l[e][d] = Wq[(size_t)i * Hc * Hc + (size_t)(et * 64 + e) * Hc + h * 64 + d];
    }
    for (int idx = t; idx < 113 * 64; idx += 256) {
        int r = idx >> 6, d = idx & 63;
        kp_l[r][d] = kp[((size_t)i * QS + r) * Hc + h * 64 + d];
    }
    __syncthreads();
    int e  = t & 63;
    int rq = t >> 6;
    for (int r = rq; r < QS; r += 4) {
        float acc = 0.f;
        #pragma unroll
        for (int d = 0; d < 64; ++d) acc += wq_l[e][d] * kp_l[r][d];
        wbig[((size_t)i * Hc + et * 64 + e) * Q4 + h * QS + r] = 0.125f * acc;
    }
}

// ---------------- merged frag prep: wcat2F | wffF | wbigF | wroF | wclsF
__global__ __launch_bounds__(64) void k_frag(const float* __restrict__ wvp2,
                                             const float* __restrict__ Wres,
                                             const float* __restrict__ Wff1,
                                             const float* __restrict__ Wff2,
                                             const float* __restrict__ wbig,
                                             const float* __restrict__ W_ro,
                                             const float* __restrict__ W_cls,
                                             unsigned short* __restrict__ wcat2F,
                                             unsigned short* __restrict__ wffF,
                                             unsigned short* __restrict__ wbigF,
                                             unsigned short* __restrict__ wroF,
                                             unsigned short* __restrict__ wclsF) {
    int blk = blockIdx.x;
    int lane = threadIdx.x;
    unsigned short v[8];
    if (blk < NLc * 192) {
        int i = blk / 192;
        int r = blk - i * 192;
        int kk = r >> 4, ct = r & 15;
        int c = ct * 16 + (lane & 15);
        int kb = kk * 32 + (lane >> 4) * 8;
        #pragma unroll
        for (int j = 0; j < 8; ++j) {
            int k = kb + j;
            float val;
            if (k < 112)      val = wvp2[((size_t)i * QS + k) * Hc + c];
            else if (k < 368) val = Wres[(size_t)i * Hc * Hc + (size_t)(k - 112) * Hc + c];
            else              val = 0.f;
            v[j] = f2bf(val);
        }
        *(uint4*)&wcat2F[(size_t)blk * 64 * 8 + lane * 8] = *(const uint4*)v;
    } else if (blk < NLc * 192 + NLc * 256) {
        int b2 = blk - NLc * 192;
        int i = b2 / 256;
        int rem = b2 - i * 256;
        int w12 = rem >> 7;
        int r = rem & 127;
        int kk = r >> 4, ct = r & 15;
        int c = ct * 16 + (lane & 15);
        int kb = kk * 32 + (lane >> 4) * 8;
        const float* src = (w12 ? Wff2 : Wff1) + (size_t)i * Hc * Hc;
        #pragma unroll
        for (int j = 0; j < 8; ++j) v[j] = f2bf(src[(size_t)(kb + j) * Hc + c]);
        *(uint4*)&wffF[(size_t)b2 * 64 * 8 + lane * 8] = *(const uint4*)v;
    } else if (blk < NLc * 192 + NLc * 256 + NLc * 232) {
        int b3 = blk - NLc * 192 - NLc * 256;
        int i = b3 / 232;
        int r = b3 - i * 232;
        int kk = r / 29, ct = r - kk * 29;
        int c = ct * 16 + (lane & 15);
        int kb = kk * 32 + (lane >> 4) * 8;
        #pragma unroll
        for (int j = 0; j < 8; ++j) {
            float val = (c < Q4) ? wbig[((size_t)i * Hc + kb + j) * Q4 + c] : 0.f;
            v[j] = f2bf(val);
        }
        *(uint4*)&wbigF[(size_t)b3 * 64 * 8 + lane * 8] = *(const uint4*)v;
    } else if (blk < NLc * 192 + NLc * 256 + NLc * 232 + 128) {
        int b4 = blk - NLc * 192 - NLc * 256 - NLc * 232;   // 0..127
        int kk = b4 >> 4, ct = b4 & 15;
        int c = ct * 16 + (lane & 15);
        int kb = kk * 32 + (lane >> 4) * 8;
        #pragma unroll
        for (int j = 0; j < 8; ++j) v[j] = f2bf(W_ro[(size_t)(kb + j) * Hc + c]);
        *(uint4*)&wroF[(size_t)b4 * 64 * 8 + lane * 8] = *(const uint4*)v;
    } else {
        int b5 = blk - NLc * 192 - NLc * 256 - NLc * 232 - 128;  // 0..15
        int kk = b5 >> 1, ct = b5 & 1;
        int c = ct * 16 + (lane & 15);
        int kb = kk * 32 + (lane >> 4) * 8;
        #pragma unroll
        for (int j = 0; j < 8; ++j) v[j] = f2bf(W_cls[(size_t)(kb + j) * Cc + c]);
        *(uint4*)&wclsF[(size_t)b5 * 64 * 8 + lane * 8] = *(const uint4*)v;
    }
}

// ---------------- h0 = [x_u, emb[act_u]] @ W_in_self + b, fused layer-0 qk2 (MFMA)
__global__ __launch_bounds__(256) void k_h0q(const float* __restrict__ x_u,
                                             const int* __restrict__ act_u,
                                             const float* __restrict__ emb,
                                             const float* __restrict__ W,
                                             const float* __restrict__ bias,
                                             const unsigned short* __restrict__ wbigF0,
                                             float* __restrict__ h,
                                             unsigned short* __restrict__ qk2b) {
    constexpr int R = 16;
    __shared__ float xu[R * Pc];
    __shared__ __align__(16) unsigned short z1n[R * 264];
    int b0 = blockIdx.x * R;
    int t = threadIdx.x;
    for (int idx = t; idx < R * Pc; idx += 256) {
        int r = idx / Pc, j = idx - r * Pc;
        int b = b0 + r;
        float v;
        if (j < Dc) v = x_u[b * Dc + j];
        else        v = emb[act_u[b] * Ec + (j - Dc)];
        xu[idx] = v;
    }
    __syncthreads();
    float acc[R];
    float bb = bias[t];
    #pragma unroll
    for (int r = 0; r < R; ++r) acc[r] = bb;
    for (int j = 0; j < Pc; ++j) {
        float w = W[j * Hc + t];
        #pragma unroll
        for (int r = 0; r < R; ++r) acc[r] += xu[r * Pc + j] * w;
    }
    #pragma unroll
    for (int r = 0; r < R; ++r) {
        h[(size_t)(b0 + r) * Hc + t] = acc[r];
        z1n[r * 264 + t] = f2bf(acc[r]);
    }
    __syncthreads();
    int wv = t >> 6, lane = t & 63;
    int n = lane & 15, kg = lane >> 4;
    for (int ct = wv; ct < 29; ct += 4) {
        f32x4 a4 = {0.f, 0.f, 0.f, 0.f};
        for (int kk = 0; kk < 8; ++kk) {
            bf16x8 a = *(const bf16x8*)&z1n[(lane & 15) * 264 + kk * 32 + kg * 8];
            bf16x8 bbv = *(const bf16x8*)(wbigF0 + (((size_t)kk * 29 + ct) * 64 + lane) * 8);
            a4 = __builtin_amdgcn_mfma_f32_16x16x32_bf16(a, bbv, a4, 0, 0, 0);
        }
        #pragma unroll
        for (int q = 0; q < 4; ++q)
            qk2b[(size_t)(b0 + kg * 4 + q) * QP + ct * 16 + n] = f2bf(a4[q]);
    }
}

// ---------------- prep (merged, R15/R17 form): xtb convert + teb + teTb. 1024 blocks.
__global__ __launch_bounds__(256) void k_prep(const float* __restrict__ x_ctx,
                                              const int* __restrict__ act_ctx,
                                              const float* __restrict__ emb,
                                              const float* __restrict__ t_ctx,
                                              const float* __restrict__ freq,
                                              const float* __restrict__ phase,
                                              unsigned short* __restrict__ xtb,
                                              unsigned short* __restrict__ teb,
                                              unsigned short* __restrict__ teTb) {
    __shared__ float lt[Lc];
    int b = blockIdx.x;
    int t = threadIdx.x;
    if (t < Lc) lt[t] = log1pf(fmaxf(t_ctx[b * Lc + t], 0.f));
    // xtb convert (no dependence on lt)
    for (int idx = t; idx < Lc * 12; idx += 256) {
        int l = idx / 12, c8 = idx - l * 12;
        int row = b * Lc + l;
        unsigned short v[8];
        if (c8 < 8) {
            const float* s = x_ctx + (size_t)row * Dc + c8 * 8;
            float4 a0 = *(const float4*)s;
            float4 a1 = *(const float4*)(s + 4);
            v[0]=f2bf(a0.x); v[1]=f2bf(a0.y); v[2]=f2bf(a0.z); v[3]=f2bf(a0.w);
            v[4]=f2bf(a1.x); v[5]=f2bf(a1.y); v[6]=f2bf(a1.z); v[7]=f2bf(a1.w);
        } else {
            int a = act_ctx[row];
            const float* s = emb + (size_t)a * Ec + (c8 - 8) * 8;
            float4 e0 = *(const float4*)s;
            float4 e1 = *(const float4*)(s + 4);
            v[0]=f2bf(e0.x); v[1]=f2bf(e0.y); v[2]=f2bf(e0.z); v[3]=f2bf(e0.w);
            v[4]=f2bf(e1.x); v[5]=f2bf(e1.y); v[6]=f2bf(e1.z); v[7]=f2bf(e1.w);
        }
        *(uint4*)&xtb[(size_t)row * 96 + c8 * 8] = *(const uint4*)v;
    }
    __syncthreads();
    for (int idx = t; idx < NLc * Lc; idx += 256) {
        int i = idx / Lc, l = idx - i * Lc;
        float L = lt[l];
        unsigned short v[16];
        #pragma unroll
        for (int j = 0; j < 8; ++j) {
            float z = L * freq[i * Tc + j] + phase[i * Tc + j];
            v[j]     = f2bf(__sinf(z));
            v[8 + j] = f2bf(__cosf(z));
        }
        size_t base = ((size_t)i * TEBS + b * Lc + l) * 16;
        *(uint4*)&teb[base]     = *(const uint4*)v;
        *(uint4*)&teb[base + 8] = *(const uint4*)&v[8];
    }
    for (int idx = t; idx < NLc * 16 * 28; idx += 256) {
        int i  = idx / 448;
        int r2 = idx - i * 448;
        int f  = r2 / 28, ch = r2 - f * 28;
        int l0 = ch * 8;
        float fr = freq[i * Tc + (f & 7)], ph = phase[i * Tc + (f & 7)];
        bool iscos = f >= 8;
        unsigned short v[8];
        #pragma unroll
        for (int k = 0; k < 8; ++k) {
            int l = l0 + k;
            float val = 0.f;
            if (l < Lc) {
                float z = lt[l] * fr + ph;
                val = iscos ? __cosf(z) : __sinf(z);
            }
            v[k] = f2bf(val);
        }
        *(uint4*)&teTb[((size_t)i * Bc * 16 + b * 16 + f) * 224 + l0] = *(const uint4*)v;
    }
}

// ---------------- fused attention (R12 form). One block per b, 8 waves.
__global__ __launch_bounds__(512) void k_att(const int* __restrict__ act_ctx,
                                             const unsigned short* __restrict__ qk2b,
                                             const unsigned short* __restrict__ xtb,
                                             const unsigned short* __restrict__ teb_l,
                                             const unsigned short* __restrict__ teTb_l,
                                             float* __restrict__ cagg) {
    constexpr int XS = 112;
    __shared__ __align__(16) unsigned short xt[208 * XS];
    __shared__ unsigned short qks[QP];
    __shared__ float S[4][208];
    __shared__ unsigned short Pl[16][232];
    int b = blockIdx.x;
    int t = threadIdx.x;
    int wv = t >> 6, lane = t & 63;
    int kg = lane >> 4;

    if (t < QP / 2) ((unsigned int*)qks)[t] = ((const unsigned int*)(qk2b + (size_t)b * QP))[t];
    for (int idx = t; idx < 16 * 29; idx += 512) {
        int row = idx / 29, c8 = idx - row * 29;
        uint4 z = {0, 0, 0, 0};
        *(uint4*)&Pl[row][c8 * 8] = z;
    }
    const unsigned short* xrow = xtb + (size_t)b * Lc * 96;
    for (int idx = t; idx < Lc * 12; idx += 512) {
        int l = idx / 12, c8 = idx - l * 12;
        uint4 v = *(const uint4*)(xrow + (size_t)l * 96 + c8 * 8);
        *(uint4*)&xt[l * XS + c8 * 8] = v;
    }
    for (int idx = t; idx < 8 * 12; idx += 512) {
        int l = 200 + idx / 12, c8 = idx - (idx / 12) * 12;
        uint4 z = {0, 0, 0, 0};
        *(uint4*)&xt[l * XS + c8 * 8] = z;
    }
    __syncthreads();

    bf16x8 bfr[4];
    {
        int h = lane & 15;
        int kb = kg * 8;
        #pragma unroll
        for (int kk = 0; kk < 4; ++kk) {
            unsigned short tmp[8];
            #pragma unroll
            for (int j = 0; j < 8; ++j) {
                int k = kk * 32 + kb + j;
                tmp[j] = (h < 4 && k < QS) ? qks[h * QS + k] : (unsigned short)0;
            }
            bfr[kk] = *(const bf16x8*)tmp;
        }
    }

    const unsigned short* terow = teb_l + (size_t)b * Lc * 16;
    for (int tile = wv; tile < 13; tile += 8) {
        int r = tile * 16 + (lane & 15);
        bf16x8 a0 = *(const bf16x8*)&xt[r * XS + kg * 8];
        bf16x8 a1 = *(const bf16x8*)&xt[r * XS + 32 + kg * 8];
        bf16x8 a2 = *(const bf16x8*)&xt[r * XS + 64 + kg * 8];
        bf16x8 a3;
        if (kg < 2) {
            a3 = *(const bf16x8*)(terow + (size_t)r * 16 + kg * 8);
        } else if (kg == 2) {
            unsigned short tmp[8] = {0x3F80u, 0, 0, 0, 0, 0, 0, 0};
            a3 = *(const bf16x8*)tmp;
        } else {
            bf16x8 z = {0, 0, 0, 0, 0, 0, 0, 0};
            a3 = z;
        }
        f32x4 acc = {0.f, 0.f, 0.f, 0.f};
        acc = __builtin_amdgcn_mfma_f32_16x16x32_bf16(a0, bfr[0], acc, 0, 0, 0);
        acc = __builtin_amdgcn_mfma_f32_16x16x32_bf16(a1, bfr[1], acc, 0, 0, 0);
        acc = __builtin_amdgcn_mfma_f32_16x16x32_bf16(a2, bfr[2], acc, 0, 0, 0);
        acc = __builtin_amdgcn_mfma_f32_16x16x32_bf16(a3, bfr[3], acc, 0, 0, 0);
        int h = lane & 15;
        if (h < 4) {
            int rb = tile * 16 + kg * 4;
            #pragma unroll
            for (int q = 0; q < 4; ++q) S[h][rb + q] = acc[q];
        }
    }
    __syncthreads();

    if (wv < 4) {
        int h = wv;
        float lv[4];
        #pragma unroll
        for (int k = 0; k < 4; ++k) {
            int l = lane + 64 * k;
            if (l < Lc) lv[k] = (act_ctx[b * Lc + l] > 0) ? S[h][l] : NEG_BIG;
            else        lv[k] = -INFINITY;
        }
        float m = fmaxf(fmaxf(lv[0], lv[1]), fmaxf(lv[2], lv[3]));
        #pragma unroll
        for (int off = 32; off >= 1; off >>= 1) m = fmaxf(m, __shfl_xor(m, off));
        float p[4];
        float ssum = 0.f;
        #pragma unroll
        for (int k = 0; k < 4; ++k) {
            int l = lane + 64 * k;
            p[k] = (l < Lc) ? __expf(lv[k] - m) : 0.f;
            ssum += p[k];
        }
        #pragma unroll
        for (int off = 32; off >= 1; off >>= 1) ssum += __shfl_xor(ssum, off);
        float sinv = 1.f / ssum;
        #pragma unroll
        for (int k = 0; k < 4; ++k) {
            int l = lane + 64 * k;
            if (l < Lc) Pl[wv][l] = f2bf(p[k] * sinv);
        }
    }
    __syncthreads();

    const unsigned short* teT = teTb_l + (size_t)b * 16 * 224;
    if (wv < 7) {
        int tile = wv;
        int n = lane & 15;
        f32x4 acc = {0.f, 0.f, 0.f, 0.f};
        #pragma unroll
        for (int kk = 0; kk < 7; ++kk) {
            bf16x8 a = *(const bf16x8*)&Pl[lane & 15][kk * 32 + kg * 8];
            bf16x8 bb;
            if (tile < 6) {
                unsigned short tmp[8];
                #pragma unroll
                for (int jj = 0; jj < 8; ++jj)
                    tmp[jj] = xt[(kk * 32 + kg * 8 + jj) * XS + tile * 16 + n];
                bb = *(const bf16x8*)tmp;
            } else {
                bb = *(const bf16x8*)(teT + (size_t)n * 224 + kk * 32 + kg * 8);
            }
            acc = __builtin_amdgcn_mfma_f32_16x16x32_bf16(a, bb, acc, 0, 0, 0);
        }
        if (kg == 0) {
            #pragma unroll
            for (int q = 0; q < 4; ++q)
                cagg[(size_t)b * CGW + q * CG + tile * 16 + n] = acc[q];
        }
    }
}

// ---------------- fused post chain + next-layer qk2 (or head on last layer).
__global__ __launch_bounds__(512) void k_postq(const float* __restrict__ cagg,
                                               float* __restrict__ h,
                                               const float* __restrict__ wvp2L,
                                               const unsigned short* __restrict__ wcat2F_l,
                                               const unsigned short* __restrict__ wff1F_l,
                                               const unsigned short* __restrict__ wff2F_l,
                                               const float* __restrict__ bresL,
                                               const float* __restrict__ bff1L,
                                               const float* __restrict__ bff2L,
                                               const float* __restrict__ g1L,
                                               const float* __restrict__ beta1L,
                                               const float* __restrict__ g2L,
                                               const float* __restrict__ beta2L,
                                               const unsigned short* __restrict__ wbigF_next,
                                               unsigned short* __restrict__ qk2b,
                                               const unsigned short* __restrict__ wroF,
                                               const unsigned short* __restrict__ wclsF,
                                               const float* __restrict__ b_ro,
                                               const float* __restrict__ b_cls,
                                               const float* __restrict__ W_dt,
                                               const float* __restrict__ b_dt,
                                               const float* __restrict__ W_rem,
                                               const float* __restrict__ b_rem,
                                               float* __restrict__ out) {
    __shared__ __align__(16) unsigned short Xa[16 * 712];
    __shared__ float z1f[16 * 260];
    __shared__ __align__(16) unsigned short z1n[16 * 264];
    __shared__ __align__(16) unsigned short fb16[16 * 264];
    int r0 = blockIdx.x * 16;
    int t = threadIdx.x;
    int wv = t >> 6, lane = t & 63;
    int n = lane & 15, kg = lane >> 4;
    const bf16x8 zf = {0, 0, 0, 0, 0, 0, 0, 0};

    for (int idx = t; idx < 16 * 704; idx += 512) {
        int r = idx / 704, c = idx - r * 704;
        float v = (c < 448) ? cagg[(size_t)(r0 + r) * CGW + c]
                            : h[(size_t)(r0 + r) * Hc + (c - 448)];
        Xa[r * 712 + c] = f2bf(v);
    }
    __syncthreads();

    // GEMM1: block-diagonal, K=384.
    {
        int hh = wv >> 1;
        f32x4 acc0 = {0.f,0.f,0.f,0.f}, acc1 = {0.f,0.f,0.f,0.f};
        #pragma unroll
        for (int kk = 0; kk < 12; ++kk) {
            int k0 = kk * 32 + kg * 8;
            bf16x8 a;
            if (k0 < 112)      a = *(const bf16x8*)&Xa[(lane & 15) * 712 + hh * 112 + k0];
            else if (k0 < 368) a = *(const bf16x8*)&Xa[(lane & 15) * 712 + 448 + (k0 - 112)];
            else               a = zf;
            bf16x8 b0 = *(const bf16x8*)(wcat2F_l + (((size_t)kk * 16 + wv * 2) * 64 + lane) * 8);
            bf16x8 b1 = *(const bf16x8*)(wcat2F_l + (((size_t)kk * 16 + wv * 2 + 1) * 64 + lane) * 8);
            acc0 = __builtin_amdgcn_mfma_f32_16x16x32_bf16(a, b0, acc0, 0, 0, 0);
            acc1 = __builtin_amdgcn_mfma_f32_16x16x32_bf16(a, b1, acc1, 0, 0, 0);
        }
        int c0 = (wv * 2) * 16 + n, c1 = (wv * 2 + 1) * 16 + n;
        float bi0 = bresL[c0] + wvp2L[112 * Hc + c0];
        float bi1 = bresL[c1] + wvp2L[112 * Hc + c1];
        #pragma unroll
        for (int q = 0; q < 4; ++q) {
            z1f[(kg * 4 + q) * 260 + c0] = acc0[q] + bi0;
            z1f[(kg * 4 + q) * 260 + c1] = acc1[q] + bi1;
        }
    }
    __syncthreads();
    if (wv < 4) {
        int row = wv * 4 + kg;
        float sm = 0.f, sq = 0.f, vals[16];
        #pragma unroll
        for (int s = 0; s < 16; ++s) {
            float v = z1f[row * 260 + n + 16 * s];
            vals[s] = v; sm += v; sq += v * v;
        }
        #pragma unroll
        for (int off = 8; off >= 1; off >>= 1) { sm += __shfl_xor(sm, off); sq += __shfl_xor(sq, off); }
        float mu = sm * (1.f / 256.f);
        float rstd = rsqrtf(sq * (1.f / 256.f) - mu * mu + LN_EPS_V);
        #pragma unroll
        for (int s = 0; s < 16; ++s) {
            int c = n + 16 * s;
            float v = (vals[s] - mu) * rstd * g1L[c] + beta1L[c];
            z1f[row * 260 + c] = v;
            z1n[row * 264 + c] = f2bf(v);
        }
    }
    __syncthreads();
    // GEMM2 (FF1) -> relu
    {
        f32x4 acc0 = {0.f,0.f,0.f,0.f}, acc1 = {0.f,0.f,0.f,0.f};
        for (int kk = 0; kk < 8; ++kk) {
            bf16x8 a = *(const bf16x8*)&z1n[(lane & 15) * 264 + kk * 32 + kg * 8];
            bf16x8 b0 = *(const bf16x8*)(wff1F_l + (((size_t)kk * 16 + wv * 2) * 64 + lane) * 8);
            bf16x8 b1 = *(const bf16x8*)(wff1F_l + (((size_t)kk * 16 + wv * 2 + 1) * 64 + lane) * 8);
            acc0 = __builtin_amdgcn_mfma_f32_16x16x32_bf16(a, b0, acc0, 0, 0, 0);
            acc1 = __builtin_amdgcn_mfma_f32_16x16x32_bf16(a, b1, acc1, 0, 0, 0);
        }
        int c0 = (wv * 2) * 16 + n, c1 = (wv * 2 + 1) * 16 + n;
        float bi0 = bff1L[c0], bi1 = bff1L[c1];
        #pragma unroll
        for (int q = 0; q < 4; ++q) {
            fb16[(kg * 4 + q) * 264 + c0] = f2bf(fmaxf(acc0[q] + bi0, 0.f));
            fb16[(kg * 4 + q) * 264 + c1] = f2bf(fmaxf(acc1[q] + bi1, 0.f));
        }
    }
    __syncthreads();
    // GEMM3 (FF2) + residual
    {
        f32x4 acc0 = {0.f,0.f,0.f,0.f}, acc1 = {0.f,0.f,0.f,0.f};
        for (int kk = 0; kk < 8; ++kk) {
            bf16x8 a = *(const bf16x8*)&fb16[(lane & 15) * 264 + kk * 32 + kg * 8];
            bf16x8 b0 = *(const bf16x8*)(wff2F_l + (((size_t)kk * 16 + wv * 2) * 64 + lane) * 8);
            bf16x8 b1 = *(const bf16x8*)(wff2F_l + (((size_t)kk * 16 + wv * 2 + 1) * 64 + lane) * 8);
            acc0 = __builtin_amdgcn_mfma_f32_16x16x32_bf16(a, b0, acc0, 0, 0, 0);
            acc1 = __builtin_amdgcn_mfma_f32_16x16x32_bf16(a, b1, acc1, 0, 0, 0);
        }
        int c0 = (wv * 2) * 16 + n, c1 = (wv * 2 + 1) * 16 + n;
        float bi0 = bff2L[c0], bi1 = bff2L[c1];
        #pragma unroll
        for (int q = 0; q < 4; ++q) {
            int row = kg * 4 + q;
            z1f[row * 260 + c0] = acc0[q] + bi0 + z1f[row * 260 + c0];
            z1f[row * 260 + c1] = acc1[q] + bi1 + z1f[row * 260 + c1];
        }
    }
    __syncthreads();
    // LN2 -> h + z1n
    if (wv < 4) {
        int row = wv * 4 + kg;
        float sm = 0.f, sq = 0.f, vals[16];
        #pragma unroll
        for (int s = 0; s < 16; ++s) {
            float v = z1f[row * 260 + n + 16 * s];
            vals[s] = v; sm += v; sq += v * v;
        }
        #pragma unroll
        for (int off = 8; off >= 1; off >>= 1) { sm += __shfl_xor(sm, off); sq += __shfl_xor(sq, off); }
        float mu = sm * (1.f / 256.f);
        float rstd = rsqrtf(sq * (1.f / 256.f) - mu * mu + LN_EPS_V);
        #pragma unroll
        for (int s = 0; s < 16; ++s) {
            int c = n + 16 * s;
            float v = (vals[s] - mu) * rstd * g2L[c] + beta2L[c];
            h[(size_t)(r0 + row) * Hc + c] = v;
            z1n[row * 264 + c] = f2bf(v);
        }
    }
    __syncthreads();
    if (wbigF_next) {
        for (int ct = wv; ct < 29; ct += 8) {
            f32x4 acc = {0.f, 0.f, 0.f, 0.f};
            for (int kk = 0; kk < 8; ++kk) {
                bf16x8 a = *(const bf16x8*)&z1n[(lane & 15) * 264 + kk * 32 + kg * 8];
                bf16x8 bb = *(const bf16x8*)(wbigF_next + (((size_t)kk * 29 + ct) * 64 + lane) * 8);
                acc = __builtin_amdgcn_mfma_f32_16x16x32_bf16(a, bb, acc, 0, 0, 0);
            }
            #pragma unroll
            for (int q = 0; q < 4; ++q)
                qk2b[(size_t)(r0 + kg * 4 + q) * QP + ct * 16 + n] = f2bf(acc[q]);
        }
    } else {
        // ---- fused head ----
        {
            f32x4 acc0 = {0.f,0.f,0.f,0.f}, acc1 = {0.f,0.f,0.f,0.f};
            for (int kk = 0; kk < 8; ++kk) {
                bf16x8 a = *(const bf16x8*)&z1n[(lane & 15) * 264 + kk * 32 + kg * 8];
                bf16x8 b0 = *(const bf16x8*)(wroF + (((size_t)kk * 16 + wv * 2) * 64 + lane) * 8);
                bf16x8 b1 = *(const bf16x8*)(wroF + (((size_t)kk * 16 + wv * 2 + 1) * 64 + lane) * 8);
                acc0 = __builtin_amdgcn_mfma_f32_16x16x32_bf16(a, b0, acc0, 0, 0, 0);
                acc1 = __builtin_amdgcn_mfma_f32_16x16x32_bf16(a, b1, acc1, 0, 0, 0);
            }
            int c0 = (wv * 2) * 16 + n, c1 = (wv * 2 + 1) * 16 + n;
            float bi0 = b_ro[c0], bi1 = b_ro[c1];
            #pragma unroll
            for (int q = 0; q < 4; ++q) {
                fb16[(kg * 4 + q) * 264 + c0] = f2bf(fmaxf(acc0[q] + bi0, 0.f));
                fb16[(kg * 4 + q) * 264 + c1] = f2bf(fmaxf(acc1[q] + bi1, 0.f));
            }
        }
        __syncthreads();
        if (wv < 2) {
            int ct = wv;
            f32x4 acc = {0.f, 0.f, 0.f, 0.f};
            for (int kk = 0; kk < 8; ++kk) {
                bf16x8 a = *(const bf16x8*)&fb16[(lane & 15) * 264 + kk * 32 + kg * 8];
                bf16x8 bb = *(const bf16x8*)(wclsF + (((size_t)kk * 2 + ct) * 64 + lane) * 8);
                acc = __builtin_amdgcn_mfma_f32_16x16x32_bf16(a, bb, acc, 0, 0, 0);
            }
            int c = ct * 16 + n;
            float bc = b_cls[c];
            #pragma unroll
            for (int q = 0; q < 4; ++q)
                out[(size_t)(r0 + kg * 4 + q) * Cc + c] = acc[q] + bc;
        }
        #pragma unroll
        for (int u = 0; u < 2; ++u) {
            int row = wv * 2 + u;
            float sd = 0.f, sr = 0.f;
            #pragma unroll
            for (int k2 = 0; k2 < 4; ++k2) {
                int c = lane + 64 * k2;
                float zv = bf2f(fb16[row * 264 + c]);
                sd += zv * W_dt[c];
                sr += zv * W_rem[c];
            }
            #pragma unroll
            for (int off = 32; off >= 1; off >>= 1) { sd += __shfl_xor(sd, off); sr += __shfl_xor(sr, off); }
            if (lane == 0) {
                out[(size_t)Bc * Cc + (r0 + row)]      = 1.f / (1.f + __expf(-(sd + b_dt[0])));
                out[(size_t)Bc * Cc + Bc + (r0 + row)] = 1.f / (1.f + __expf(-(sr + b_rem[0])));
            }
        }
    }
}

extern "C" void kernel_launch(void* const* d_in, const int* in_sizes, int n_in,
                              void* d_out, int out_size, void* d_ws, size_t ws_size,
                              hipStream_t stream) {
    const float* x_u      = (const float*)d_in[0];
    const float* x_ctx    = (const float*)d_in[1];
    const float* t_ctx    = (const float*)d_in[2];
    const int*   act_u    = (const int*)d_in[3];
    const int*   act_ctx  = (const int*)d_in[4];
    const float* emb      = (const float*)d_in[5];
    const float* W_in_self = (const float*)d_in[6];
    const float* b_in_self = (const float*)d_in[7];
    const float* W_in_ctx  = (const float*)d_in[8];
    const float* b_in_ctx  = (const float*)d_in[9];
    const float* freq  = (const float*)d_in[10];
    const float* phase = (const float*)d_in[11];
    const float* Wq    = (const float*)d_in[12];
    const float* Wk    = (const float*)d_in[13];
    const float* Wv    = (const float*)d_in[14];
    const float* Wres  = (const float*)d_in[15];
    const float* bres  = (const float*)d_in[16];
    const float* Wff1  = (const float*)d_in[17];
    const float* bff1  = (const float*)d_in[18];
    const float* Wff2  = (const float*)d_in[19];
    const float* bff2  = (const float*)d_in[20];
    const float* g1    = (const float*)d_in[21];
    const float* beta1 = (const float*)d_in[22];
    const float* g2    = (const float*)d_in[23];
    const float* beta2 = (const float*)d_in[24];
    const float* W_ro  = (const float*)d_in[25];
    const float* b_ro  = (const float*)d_in[26];
    const float* W_cls = (const float*)d_in[27];
    const float* b_cls = (const float*)d_in[28];
    const float* W_dt  = (const float*)d_in[29];
    const float* b_dt  = (const float*)d_in[30];
    const float* W_rem = (const float*)d_in[31];
    const float* b_rem = (const float*)d_in[32];

    float* ws    = (float*)d_ws;
    float* hbuf  = ws;                                    // B*H
    float* wbig  = hbuf  + (size_t)Bc * Hc;               // NL*H*Q4
    float* cagg2 = wbig  + (size_t)NLc * Hc * Q4;         // B*CGW
    float* wvp2  = cagg2 + (size_t)Bc * CGW;              // NL*QS*H
    float* kp    = wvp2  + (size_t)NLc * QS * Hc;         // NL*QS*H
    unsigned short* xtb   = (unsigned short*)(kp + (size_t)NLc * QS * Hc);
    unsigned short* teb   = xtb   + (size_t)Bc * Lc * 96;
    unsigned short* teTb  = teb   + (size_t)NLc * TEBS * 16;
    unsigned short* qk2b  = teTb  + (size_t)NLc * Bc * 16 * 224;
    unsigned short* wcat2F = qk2b + (size_t)Bc * QP;      // NL*192*512
    unsigned short* wffF  = wcat2F + (size_t)NLc * 192 * 512;
    unsigned short* wbigF = wffF  + (size_t)NLc * 2 * 128 * 512;
    unsigned short* wroF  = wbigF + (size_t)NLc * 232 * 512;   // 128*512
    unsigned short* wclsF = wroF  + (size_t)128 * 512;         // 16*512
    size_t need = ((size_t)Bc * Hc + (size_t)NLc * Hc * Q4
                  + (size_t)Bc * CGW + 2 * (size_t)NLc * QS * Hc) * 4
                + ((size_t)Bc * Lc * 96
                  + (size_t)NLc * TEBS * 16 + (size_t)NLc * Bc * 16 * 224
                  + (size_t)Bc * QP
                  + (size_t)NLc * 192 * 512 + (size_t)NLc * 2 * 128 * 512
                  + (size_t)NLc * 232 * 512 + (size_t)144 * 512) * 2;
    if (ws_size < need) return;

    float* out = (float*)d_out;

    k_kpv<<<NLc * QS, 256, 0, stream>>>(W_in_ctx, b_in_ctx, Wv, Wk, wvp2, kp);
    k_wbig2<<<NLc * 16, 256, 0, stream>>>(Wq, kp, wbig);
    k_frag<<<NLc * (192 + 256 + 232) + 144, 64, 0, stream>>>(wvp2, Wres, Wff1, Wff2, wbig,
                                                             W_ro, W_cls,
                                                             wcat2F, wffF, wbigF, wroF, wclsF);
    k_prep<<<Bc, 256, 0, stream>>>(x_ctx, act_ctx, emb, t_ctx, freq, phase, xtb, teb, teTb);
    k_h0q<<<Bc / 16, 256, 0, stream>>>(x_u, act_u, emb, W_in_self, b_in_self,
                                       wbigF, hbuf, qk2b);

    for (int i = 0; i < NLc; ++i) {
        k_att<<<Bc, 512, 0, stream>>>(act_ctx, qk2b, xtb,
                                      teb + (size_t)i * TEBS * 16,
                                      teTb + (size_t)i * Bc * 16 * 224, cagg2);
        const unsigned short* wbnext = (i < NLc - 1) ? (wbigF + (size_t)(i + 1) * 232 * 512)
                                                     : (const unsigned short*)nullptr;
        k_postq<<<Bc / 16, 512, 0, stream>>>(cagg2, hbuf,
                                             wvp2 + (size_t)i * QS * Hc,
                                             wcat2F + (size_t)i * 192 * 512,
                                             wffF + (size_t)(i * 2) * 128 * 512,
                                             wffF + (size_t)(i * 2 + 1) * 128 * 512,
                                             bres + i * Hc, bff1 + i * Hc, bff2 + i * Hc,
                                             g1 + i * Hc, beta1 + i * Hc,
                                             g2 + i * Hc, beta2 + i * Hc,
                                             wbnext, qk2b,
                                             wroF, wclsF, b_ro, b_cls,
                                             W_dt, b_dt, W_rem, b_rem, out);
    }
}